// Round 10
// baseline (160.953 us; speedup 1.0000x reference)
//
#include <hip/hip_runtime.h>

// ---------------- types ----------------
typedef __attribute__((ext_vector_type(8))) short bf16x8;   // 8 bf16 in 4 VGPRs
typedef __attribute__((ext_vector_type(4))) float f32x4;
typedef __attribute__((ext_vector_type(8))) unsigned short us8;

#define K_DIM 2048
#define QK_N  320     // 256 q cols + 64 k cols
#define SEQ   4096
#define BK    64
#define NCHUNK 32                      // K_DIM / BK
#define NHALF  160                     // N columns per block
#define BCHUNK 20480                   // bytes of one B chunk: 8 units * 160 cols * 16B
#define STRIP_BYTES 131072             // 32 rows * 2048 k * 2B = 64 t-steps * 2048B

__device__ __forceinline__ unsigned short f2bf(float f) {
    unsigned int u = __builtin_bit_cast(unsigned int, f);
    u += 0x7FFFu + ((u >> 16) & 1u);      // round-to-nearest-even
    return (unsigned short)(u >> 16);
}

// ---------------- W convert + re-layout ----------------
// ws layout: [2 N-halves][NCHUNK][8 k-units][160 cols][16B]
__global__ void cvt_w_swz(const float* __restrict__ Wq,
                          const float* __restrict__ Wk,
                          unsigned short* __restrict__ ws) {
    int id = blockIdx.x * 256 + threadIdx.x;   // 320*256 ids
    int c  = id >> 8;                          // 0..319 (output col)
    int k8 = id & 255;                         // 8-elem k group
    int k0 = k8 * 8;
    const float* src = (c < 256) ? (Wq + (size_t)c * K_DIM + k0)
                                 : (Wk + (size_t)(c - 256) * K_DIM + k0);
    float4 v0 = *reinterpret_cast<const float4*>(src);
    float4 v1 = *reinterpret_cast<const float4*>(src + 4);
    us8 o;
    o[0] = f2bf(v0.x); o[1] = f2bf(v0.y); o[2] = f2bf(v0.z); o[3] = f2bf(v0.w);
    o[4] = f2bf(v1.x); o[5] = f2bf(v1.y); o[6] = f2bf(v1.z); o[7] = f2bf(v1.w);
    int half = (c >= NHALF) ? 1 : 0;
    int cc   = c - half * NHALF;
    int kc = k0 / BK;            // chunk index 0..31
    int u  = (k0 % BK) >> 3;     // k-unit within chunk (0..7)
    size_t byteoff = (size_t)half * (NCHUNK * (size_t)BCHUNK)
                   + (size_t)kc * BCHUNK + ((size_t)(u * NHALF + cc) * 16);
    *reinterpret_cast<us8*>((char*)ws + byteoff) = o;
}

// ---------------- h convert + re-layout via LDS transpose ----------------
// Output layout (identical to round 9): [256 strips][64 t][2 rg][64 lanes][16B]
// where lane=(lg*16+lr), row=rg*16+lr, cols=t*32+lg*8.
// LDS transpose: global reads row-major coalesced (2KB/wave), LDS XOR-swizzled
// (G4: byte ^= (row&7)<<4) so frag-order reads are conflict-light, global
// writes perfectly contiguous (1KB/wave). No strided HBM access on either side.
__global__ __launch_bounds__(512) void cvt_h_swz(
    const float* __restrict__ h, char* __restrict__ hs) {
    __shared__ char L[32 * 1024];             // [32 rows][512 bf16] swizzled
    const int strip = blockIdx.x;
    const float* hbase = h + (size_t)strip * 32 * K_DIM;
    char* obase = hs + (size_t)strip * STRIP_BYTES;

    for (int q = 0; q < 4; ++q) {             // k-quarter: cols [q*512, q*512+512)
        // phase 1: coalesced read + cvt -> LDS
#pragma unroll
        for (int i = 0; i < 4; ++i) {
            int u = i * 512 + threadIdx.x;    // 0..2047
            int r = u >> 6;                   // row 0..31
            int g = u & 63;                   // 8-col group 0..63
            const float* src = hbase + (size_t)r * K_DIM + q * 512 + g * 8;
            float4 v0 = *reinterpret_cast<const float4*>(src);
            float4 v1 = *reinterpret_cast<const float4*>(src + 4);
            us8 o;
            o[0] = f2bf(v0.x); o[1] = f2bf(v0.y); o[2] = f2bf(v0.z); o[3] = f2bf(v0.w);
            o[4] = f2bf(v1.x); o[5] = f2bf(v1.y); o[6] = f2bf(v1.z); o[7] = f2bf(v1.w);
            int byteoff = r * 1024 + ((g * 16) ^ ((r & 7) << 4));
            *reinterpret_cast<us8*>(L + byteoff) = o;
        }
        __syncthreads();
        // phase 2: LDS -> global in fragment order, contiguous stores
#pragma unroll
        for (int i = 0; i < 4; ++i) {
            int u = i * 512 + threadIdx.x;    // 16B units 0..2047
            int tt  = u >> 7;                 // local t-step 0..15
            int rem = u & 127;
            int rg  = rem >> 6;
            int lane = rem & 63;
            int lg = lane >> 4, lr = lane & 15;
            int row = rg * 16 + lr;
            int lcol16 = tt * 4 + lg;         // 16B slot within row
            int byteoff = row * 1024 + ((lcol16 * 16) ^ ((row & 7) << 4));
            us8 o = *reinterpret_cast<const us8*>(L + byteoff);
            size_t oo = (size_t)(q * 16 + tt) * 2048 + (size_t)rg * 1024
                      + (size_t)lane * 16;
            *reinterpret_cast<us8*>(obase + oo) = o;
        }
        __syncthreads();
    }
}

// ---------------- projection GEMM: QKb[8192][320] = h * W^T (bf16 out) -------
// grid (2 N-halves, 256 M-strips) = 512 blocks x 256 threads (4 waves:
// 2 rg x 2 cg). block tile 32x160 over K=2048. No LDS, no barriers.
// A-frags: ONE contiguous 1KB-per-wave dwordx4 per t-step from h_swz (streams
// linearly). B-frags: L2-resident pre-swizzled W. 1-deep register ping-pong.
__global__ __launch_bounds__(256, 2) void proj_gemm(
    const char* __restrict__ Hs,            // h_swz (bf16 frag order)
    const unsigned short* __restrict__ Wsz, // re-laid-out W
    unsigned short* __restrict__ C)         // [8192][320] bf16
{
    const int tid  = threadIdx.x;
    const int lane = tid & 63;
    const int wid  = tid >> 6;          // 0..3
    const int rg   = wid >> 1;          // 0..1 (M row-group)
    const int cg   = wid & 1;           // 0..1 (N col-group)
    const int half = blockIdx.x;
    const int row0 = blockIdx.y * 32 + rg * 16;
    const int lr = lane & 15, lg = lane >> 4;

    // A: contiguous per-wave fragment stream
    const char* ahp = Hs + (size_t)blockIdx.y * STRIP_BYTES
                    + (size_t)rg * 1024 + (size_t)lane * 16;
    const char* wbase = (const char*)Wsz + (size_t)half * (NCHUNK * (size_t)BCHUNK)
                      + ((cg * 80 + lr) << 4);

    f32x4 acc[5];
#pragma unroll
    for (int j = 0; j < 5; ++j) acc[j] = (f32x4)0.f;

#define LOADB(t, b0, b1, b2, b3, b4) do {                                   \
        const char* bu = wbase + (size_t)((t) >> 1) * BCHUNK                \
                       + (size_t)((((t) & 1) * 4 + lg) * NHALF) * 16;       \
        b0 = *reinterpret_cast<const bf16x8*>(bu);                          \
        b1 = *reinterpret_cast<const bf16x8*>(bu + 256);                    \
        b2 = *reinterpret_cast<const bf16x8*>(bu + 512);                    \
        b3 = *reinterpret_cast<const bf16x8*>(bu + 768);                    \
        b4 = *reinterpret_cast<const bf16x8*>(bu + 1024);                   \
    } while (0)
#define LOADA(t, a) do {                                                    \
        a = *reinterpret_cast<const bf16x8*>(ahp + (size_t)(t) * 2048);     \
    } while (0)
#define COMPUTE(a, b0, b1, b2, b3, b4) do {                                 \
        acc[0] = __builtin_amdgcn_mfma_f32_16x16x32_bf16(a, b0, acc[0], 0, 0, 0); \
        acc[1] = __builtin_amdgcn_mfma_f32_16x16x32_bf16(a, b1, acc[1], 0, 0, 0); \
        acc[2] = __builtin_amdgcn_mfma_f32_16x16x32_bf16(a, b2, acc[2], 0, 0, 0); \
        acc[3] = __builtin_amdgcn_mfma_f32_16x16x32_bf16(a, b3, acc[3], 0, 0, 0); \
        acc[4] = __builtin_amdgcn_mfma_f32_16x16x32_bf16(a, b4, acc[4], 0, 0, 0); \
    } while (0)

    // ping-pong register sets (static names — rule #20)
    bf16x8 cb0, cb1, cb2, cb3, cb4, ca;
    bf16x8 nb0, nb1, nb2, nb3, nb4, na;

    LOADB(0, cb0, cb1, cb2, cb3, cb4);
    LOADA(0, ca);

    for (int t = 0; t < 64; t += 2) {
        // issue t+1 loads, then compute t
        LOADB(t + 1, nb0, nb1, nb2, nb3, nb4);
        LOADA(t + 1, na);
        COMPUTE(ca, cb0, cb1, cb2, cb3, cb4);
        // issue t+2 loads (clamped), then compute t+1
        const int t2 = (t + 2 < 64) ? t + 2 : 63;
        LOADB(t2, cb0, cb1, cb2, cb3, cb4);
        LOADA(t2, ca);
        COMPUTE(na, nb0, nb1, nb2, nb3, nb4);
    }
#undef LOADB
#undef LOADA
#undef COMPUTE

    // epilogue: C layout col=lane&15, row=(lane>>4)*4+r
    const int crow = row0 + lg * 4;
    const int ccol = half * NHALF + cg * 80 + lr;
#pragma unroll
    for (int j = 0; j < 5; ++j)
#pragma unroll
        for (int r = 0; r < 4; ++r)
            C[(size_t)(crow + r) * QK_N + ccol + j * 16] = f2bf(acc[j][r]);
}

// ---------------- scores: I[b,t,s] = sum_h w[h]*relu(Q_h K^T) ----------------
// grid (32,32,2); block 256 = 4 waves (2x2). block tile 128x128, wave tile 64x64.
// MFMA operands swapped (a=K-frag, b=Q-frag) so each lane's 4 acc regs are 4
// consecutive s values -> float4 stores.
__global__ __launch_bounds__(256) void scores_kernel(
    const unsigned short* __restrict__ QK,   // [B][4096][320] bf16
    const float* __restrict__ w,             // [4]
    float* __restrict__ out)                 // [B][4096][4096] fp32
{
    const int lane = threadIdx.x & 63;
    const int wid  = threadIdx.x >> 6;
    const int b  = blockIdx.z;
    const int t0 = blockIdx.y * 128 + (wid >> 1) * 64;
    const int s0 = blockIdx.x * 128 + (wid & 1) * 64;

    const int lr = lane & 15;
    const int lk = (lane >> 4) * 8;
    const int lg = lane >> 4;

    const unsigned short* Qb = QK + (size_t)b * SEQ * QK_N;
    const unsigned short* Kb = Qb + 256;

    float wv[4] = { w[0], w[1], w[2], w[3] };

    f32x4 fin[4][4];
#pragma unroll
    for (int i = 0; i < 4; ++i)
#pragma unroll
        for (int j = 0; j < 4; ++j) fin[i][j] = (f32x4)0.f;

    const unsigned short* qp = Qb + (size_t)(t0 + lr) * QK_N + lk;
    const unsigned short* kp = Kb + (size_t)(s0 + lr) * QK_N + lk;

#pragma unroll
    for (int h = 0; h < 4; ++h) {
        f32x4 acc[4][4];
#pragma unroll
        for (int i = 0; i < 4; ++i)
#pragma unroll
            for (int j = 0; j < 4; ++j) acc[i][j] = (f32x4)0.f;

#pragma unroll
        for (int ks = 0; ks < 2; ++ks) {
            bf16x8 qf[4], kf[4];
#pragma unroll
            for (int i = 0; i < 4; ++i)
                qf[i] = *reinterpret_cast<const bf16x8*>(
                    qp + (size_t)i * 16 * QK_N + h * 64 + ks * 32);
#pragma unroll
            for (int j = 0; j < 4; ++j)
                kf[j] = *reinterpret_cast<const bf16x8*>(
                    kp + (size_t)j * 16 * QK_N + ks * 32);
            // swapped: a=K (s in reg dim), b=Q (t on lane&15)
#pragma unroll
            for (int i = 0; i < 4; ++i)
#pragma unroll
                for (int j = 0; j < 4; ++j)
                    acc[i][j] = __builtin_amdgcn_mfma_f32_16x16x32_bf16(kf[j], qf[i], acc[i][j], 0, 0, 0);
        }
#pragma unroll
        for (int i = 0; i < 4; ++i)
#pragma unroll
            for (int j = 0; j < 4; ++j)
#pragma unroll
                for (int r = 0; r < 4; ++r)
                    fin[i][j][r] += wv[h] * fmaxf(acc[i][j][r], 0.f);
    }

    // store: lane holds t = t0+i*16+lr, s = s0+j*16+lg*4 .. +3 (contiguous)
    float* ob = out + (size_t)b * SEQ * SEQ;
#pragma unroll
    for (int i = 0; i < 4; ++i) {
        const size_t rbase = (size_t)(t0 + i * 16 + lr) * SEQ + s0 + lg * 4;
#pragma unroll
        for (int j = 0; j < 4; ++j) {
            float4 v;
            v.x = fin[i][j][0]; v.y = fin[i][j][1];
            v.z = fin[i][j][2]; v.w = fin[i][j][3];
            *reinterpret_cast<float4*>(&ob[rbase + j * 16]) = v;
        }
    }
}

// ---------------- launch ----------------
extern "C" void kernel_launch(void* const* d_in, const int* in_sizes, int n_in,
                              void* d_out, int out_size, void* d_ws, size_t ws_size,
                              hipStream_t stream) {
    const float* h  = (const float*)d_in[0];   // [2,4096,2048]
    const float* Wq = (const float*)d_in[1];   // [256,2048]
    const float* Wk = (const float*)d_in[2];   // [64,2048]
    const float* w  = (const float*)d_in[3];   // [4]
    float* out = (float*)d_out;                // [2,4096,4096]

    char* ws = (char*)d_ws;
    unsigned short* W_swz = (unsigned short*)ws;                       // 1.25 MB
    ws += 2 * (size_t)NCHUNK * BCHUNK;
    char* H_swz = ws;                                                  // 32 MB
    ws += (size_t)256 * STRIP_BYTES;
    unsigned short* QKb = (unsigned short*)ws;                         // 5 MB bf16

    cvt_w_swz<<<320, 256, 0, stream>>>(Wq, Wk, W_swz);
    cvt_h_swz<<<256, 512, 0, stream>>>(h, H_swz);
    proj_gemm<<<dim3(2, 256), 256, 0, stream>>>(H_swz, W_swz, QKb);
    scores_kernel<<<dim3(32, 32, 2), 256, 0, stream>>>(QKb, w, out);
}

// Round 11
// 120.310 us; speedup vs baseline: 1.3378x; 1.3378x over previous
//
#include <hip/hip_runtime.h>

// ---------------- types ----------------
typedef __attribute__((ext_vector_type(8))) short bf16x8;   // 8 bf16 in 4 VGPRs
typedef __attribute__((ext_vector_type(4))) float f32x4;
typedef __attribute__((ext_vector_type(8))) unsigned short us8;

#define K_DIM 2048
#define QK_N  320     // 256 q cols + 64 k cols
#define SEQ   4096
#define BK    64
#define NCHUNK 32                      // K_DIM / BK
#define NHALF  160                     // N columns per block
#define BCHUNK 20480                   // bytes of one B chunk: 8 units * 160 cols * 16B
#define STRIP_BYTES 131072             // 32 rows * 2048 k * 2B = 64 t-steps * 2048B

__device__ __forceinline__ unsigned short f2bf(float f) {
    unsigned int u = __builtin_bit_cast(unsigned int, f);
    u += 0x7FFFu + ((u >> 16) & 1u);      // round-to-nearest-even
    return (unsigned short)(u >> 16);
}

// ---------------- W convert + re-layout ----------------
// ws layout: [2 N-halves][NCHUNK][8 k-units][160 cols][16B]
__global__ void cvt_w_swz(const float* __restrict__ Wq,
                          const float* __restrict__ Wk,
                          unsigned short* __restrict__ ws) {
    int id = blockIdx.x * 256 + threadIdx.x;   // 320*256 ids
    int c  = id >> 8;                          // 0..319 (output col)
    int k8 = id & 255;                         // 8-elem k group
    int k0 = k8 * 8;
    const float* src = (c < 256) ? (Wq + (size_t)c * K_DIM + k0)
                                 : (Wk + (size_t)(c - 256) * K_DIM + k0);
    float4 v0 = *reinterpret_cast<const float4*>(src);
    float4 v1 = *reinterpret_cast<const float4*>(src + 4);
    us8 o;
    o[0] = f2bf(v0.x); o[1] = f2bf(v0.y); o[2] = f2bf(v0.z); o[3] = f2bf(v0.w);
    o[4] = f2bf(v1.x); o[5] = f2bf(v1.y); o[6] = f2bf(v1.z); o[7] = f2bf(v1.w);
    int half = (c >= NHALF) ? 1 : 0;
    int cc   = c - half * NHALF;
    int kc = k0 / BK;            // chunk index 0..31
    int u  = (k0 % BK) >> 3;     // k-unit within chunk (0..7)
    size_t byteoff = (size_t)half * (NCHUNK * (size_t)BCHUNK)
                   + (size_t)kc * BCHUNK + ((size_t)(u * NHALF + cc) * 16);
    *reinterpret_cast<us8*>((char*)ws + byteoff) = o;
}

// ---------------- h convert + re-layout via LDS transpose ----------------
// Output layout: [256 strips][64 t][2 rg][64 lanes][16B]; lane=(lg*16+lr),
// row=rg*16+lr, cols=t*32+lg*8. Reads coalesced, writes contiguous 1KB/wave.
__global__ __launch_bounds__(512) void cvt_h_swz(
    const float* __restrict__ h, char* __restrict__ hs) {
    __shared__ char L[32 * 1024];             // [32 rows][512 bf16] swizzled
    const int strip = blockIdx.x;
    const float* hbase = h + (size_t)strip * 32 * K_DIM;
    char* obase = hs + (size_t)strip * STRIP_BYTES;

    for (int q = 0; q < 4; ++q) {             // k-quarter: cols [q*512, q*512+512)
#pragma unroll
        for (int i = 0; i < 4; ++i) {
            int u = i * 512 + threadIdx.x;    // 0..2047
            int r = u >> 6;                   // row 0..31
            int g = u & 63;                   // 8-col group 0..63
            const float* src = hbase + (size_t)r * K_DIM + q * 512 + g * 8;
            float4 v0 = *reinterpret_cast<const float4*>(src);
            float4 v1 = *reinterpret_cast<const float4*>(src + 4);
            us8 o;
            o[0] = f2bf(v0.x); o[1] = f2bf(v0.y); o[2] = f2bf(v0.z); o[3] = f2bf(v0.w);
            o[4] = f2bf(v1.x); o[5] = f2bf(v1.y); o[6] = f2bf(v1.z); o[7] = f2bf(v1.w);
            int byteoff = r * 1024 + ((g * 16) ^ ((r & 7) << 4));
            *reinterpret_cast<us8*>(L + byteoff) = o;
        }
        __syncthreads();
#pragma unroll
        for (int i = 0; i < 4; ++i) {
            int u = i * 512 + threadIdx.x;    // 16B units 0..2047
            int tt  = u >> 7;                 // local t-step 0..15
            int rem = u & 127;
            int rg  = rem >> 6;
            int lane = rem & 63;
            int lg = lane >> 4, lr = lane & 15;
            int row = rg * 16 + lr;
            int lcol16 = tt * 4 + lg;         // 16B slot within row
            int byteoff = row * 1024 + ((lcol16 * 16) ^ ((row & 7) << 4));
            us8 o = *reinterpret_cast<const us8*>(L + byteoff);
            size_t oo = (size_t)(q * 16 + tt) * 2048 + (size_t)rg * 1024
                      + (size_t)lane * 16;
            *reinterpret_cast<us8*>(obase + oo) = o;
        }
        __syncthreads();
    }
}

// ---------------- projection GEMM: QKb[8192][320] = h * W^T (bf16 out) -------
// grid (2 N-halves, 256 M-strips) = 512 blocks x 256 threads (4 waves:
// 2 rg x 2 cg), wave tile 16x80, K=2048. No LDS, no barriers.
// ASM-PIPELINED: 4-deep explicit pipeline, 24 global_load_dwordx4 in flight
// per wave via inline asm (compiler cannot sink/serialize them — the failure
// mode of rounds 1-10), counted s_waitcnt vmcnt(18/12/6/0), never 0 in loop.
__global__ __launch_bounds__(256) void proj_gemm(
    const char* __restrict__ Hs,            // h_swz (bf16 frag order)
    const unsigned short* __restrict__ Wsz, // re-laid-out W
    unsigned short* __restrict__ C)         // [8192][320] bf16
{
    const int tid  = threadIdx.x;
    const int lane = tid & 63;
    const int wid  = tid >> 6;          // 0..3
    const int rg   = wid >> 1;          // 0..1 (M row-group)
    const int cg   = wid & 1;           // 0..1 (N col-group)
    const int half = blockIdx.x;
    const int row0 = blockIdx.y * 32 + rg * 16;
    const int lr = lane & 15, lg = lane >> 4;

    const char* ahp = Hs + (size_t)blockIdx.y * STRIP_BYTES
                    + (size_t)rg * 1024 + (size_t)lane * 16;
    const char* wbase = (const char*)Wsz + (size_t)half * (NCHUNK * (size_t)BCHUNK)
                      + ((cg * 80 + lr) << 4);

    f32x4 acc[5];
#pragma unroll
    for (int j = 0; j < 5; ++j) acc[j] = (f32x4)0.f;

#define GLOAD(dst, ptr) \
    asm volatile("global_load_dwordx4 %0, %1, off" : "=v"(dst) : "v"(ptr))

#define WAITV(N) do { \
    asm volatile("s_waitcnt vmcnt(" #N ")" ::: "memory"); \
    __builtin_amdgcn_sched_barrier(0); \
} while (0)

    // issue the 6 loads of t-step u into a frag set (b0..b4 first, a last)
#define ISSUE(u, fa, f0, f1, f2, f3, f4) do { \
    const char* bu_ = wbase + (size_t)((u) >> 1) * BCHUNK \
                    + (size_t)((((u) & 1) * 4 + lg) * NHALF) * 16; \
    GLOAD(f0, bu_); \
    GLOAD(f1, bu_ + 256); \
    GLOAD(f2, bu_ + 512); \
    GLOAD(f3, bu_ + 768); \
    GLOAD(f4, bu_ + 1024); \
    GLOAD(fa, ahp + (size_t)(u) * 2048); \
} while (0)

#define COMPUTE(fa, f0, f1, f2, f3, f4) do { \
    acc[0] = __builtin_amdgcn_mfma_f32_16x16x32_bf16(fa, f0, acc[0], 0, 0, 0); \
    acc[1] = __builtin_amdgcn_mfma_f32_16x16x32_bf16(fa, f1, acc[1], 0, 0, 0); \
    acc[2] = __builtin_amdgcn_mfma_f32_16x16x32_bf16(fa, f2, acc[2], 0, 0, 0); \
    acc[3] = __builtin_amdgcn_mfma_f32_16x16x32_bf16(fa, f3, acc[3], 0, 0, 0); \
    acc[4] = __builtin_amdgcn_mfma_f32_16x16x32_bf16(fa, f4, acc[4], 0, 0, 0); \
} while (0)

    // 4 frag sets (static names — rule #20): 24 bf16x8 = 96 VGPR
    bf16x8 a0, p00, p01, p02, p03, p04;
    bf16x8 a1, p10, p11, p12, p13, p14;
    bf16x8 a2, p20, p21, p22, p23, p24;
    bf16x8 a3, p30, p31, p32, p33, p34;

    // prologue: fill the pipeline (24 loads in flight)
    ISSUE(0, a0, p00, p01, p02, p03, p04);
    ISSUE(1, a1, p10, p11, p12, p13, p14);
    ISSUE(2, a2, p20, p21, p22, p23, p24);
    ISSUE(3, a3, p30, p31, p32, p33, p34);

    for (int t = 0; t < 60; t += 4) {
        WAITV(18);
        COMPUTE(a0, p00, p01, p02, p03, p04);
        ISSUE(t + 4, a0, p00, p01, p02, p03, p04);
        WAITV(18);
        COMPUTE(a1, p10, p11, p12, p13, p14);
        ISSUE(t + 5, a1, p10, p11, p12, p13, p14);
        WAITV(18);
        COMPUTE(a2, p20, p21, p22, p23, p24);
        ISSUE(t + 6, a2, p20, p21, p22, p23, p24);
        WAITV(18);
        COMPUTE(a3, p30, p31, p32, p33, p34);
        ISSUE(t + 7, a3, p30, p31, p32, p33, p34);
    }
    // epilogue: drain (t = 60..63)
    WAITV(18);
    COMPUTE(a0, p00, p01, p02, p03, p04);
    WAITV(12);
    COMPUTE(a1, p10, p11, p12, p13, p14);
    WAITV(6);
    COMPUTE(a2, p20, p21, p22, p23, p24);
    WAITV(0);
    COMPUTE(a3, p30, p31, p32, p33, p34);

#undef GLOAD
#undef WAITV
#undef ISSUE
#undef COMPUTE

    // epilogue: C layout col=lane&15, row=(lane>>4)*4+r
    const int crow = row0 + lg * 4;
    const int ccol = half * NHALF + cg * 80 + lr;
#pragma unroll
    for (int j = 0; j < 5; ++j)
#pragma unroll
        for (int r = 0; r < 4; ++r)
            C[(size_t)(crow + r) * QK_N + ccol + j * 16] = f2bf(acc[j][r]);
}

// ---------------- scores: I[b,t,s] = sum_h w[h]*relu(Q_h K^T) ----------------
// grid (32,32,2); block 256 = 4 waves (2x2). block tile 128x128, wave tile 64x64.
__global__ __launch_bounds__(256) void scores_kernel(
    const unsigned short* __restrict__ QK,   // [B][4096][320] bf16
    const float* __restrict__ w,             // [4]
    float* __restrict__ out)                 // [B][4096][4096] fp32
{
    const int lane = threadIdx.x & 63;
    const int wid  = threadIdx.x >> 6;
    const int b  = blockIdx.z;
    const int t0 = blockIdx.y * 128 + (wid >> 1) * 64;
    const int s0 = blockIdx.x * 128 + (wid & 1) * 64;

    const int lr = lane & 15;
    const int lk = (lane >> 4) * 8;
    const int lg = lane >> 4;

    const unsigned short* Qb = QK + (size_t)b * SEQ * QK_N;
    const unsigned short* Kb = Qb + 256;

    float wv[4] = { w[0], w[1], w[2], w[3] };

    f32x4 fin[4][4];
#pragma unroll
    for (int i = 0; i < 4; ++i)
#pragma unroll
        for (int j = 0; j < 4; ++j) fin[i][j] = (f32x4)0.f;

    const unsigned short* qp = Qb + (size_t)(t0 + lr) * QK_N + lk;
    const unsigned short* kp = Kb + (size_t)(s0 + lr) * QK_N + lk;

#pragma unroll
    for (int h = 0; h < 4; ++h) {
        f32x4 acc[4][4];
#pragma unroll
        for (int i = 0; i < 4; ++i)
#pragma unroll
            for (int j = 0; j < 4; ++j) acc[i][j] = (f32x4)0.f;

#pragma unroll
        for (int ks = 0; ks < 2; ++ks) {
            bf16x8 qf[4], kf[4];
#pragma unroll
            for (int i = 0; i < 4; ++i)
                qf[i] = *reinterpret_cast<const bf16x8*>(
                    qp + (size_t)i * 16 * QK_N + h * 64 + ks * 32);
#pragma unroll
            for (int j = 0; j < 4; ++j)
                kf[j] = *reinterpret_cast<const bf16x8*>(
                    kp + (size_t)j * 16 * QK_N + ks * 32);
            // swapped: a=K (s in reg dim), b=Q (t on lane&15)
#pragma unroll
            for (int i = 0; i < 4; ++i)
#pragma unroll
                for (int j = 0; j < 4; ++j)
                    acc[i][j] = __builtin_amdgcn_mfma_f32_16x16x32_bf16(kf[j], qf[i], acc[i][j], 0, 0, 0);
        }
#pragma unroll
        for (int i = 0; i < 4; ++i)
#pragma unroll
            for (int j = 0; j < 4; ++j)
#pragma unroll
                for (int r = 0; r < 4; ++r)
                    fin[i][j][r] += wv[h] * fmaxf(acc[i][j][r], 0.f);
    }

    // store: lane holds t = t0+i*16+lr, s = s0+j*16+lg*4 .. +3 (contiguous)
    float* ob = out + (size_t)b * SEQ * SEQ;
#pragma unroll
    for (int i = 0; i < 4; ++i) {
        const size_t rbase = (size_t)(t0 + i * 16 + lr) * SEQ + s0 + lg * 4;
#pragma unroll
        for (int j = 0; j < 4; ++j) {
            float4 v;
            v.x = fin[i][j][0]; v.y = fin[i][j][1];
            v.z = fin[i][j][2]; v.w = fin[i][j][3];
            *reinterpret_cast<float4*>(&ob[rbase + j * 16]) = v;
        }
    }
}

// ---------------- launch ----------------
extern "C" void kernel_launch(void* const* d_in, const int* in_sizes, int n_in,
                              void* d_out, int out_size, void* d_ws, size_t ws_size,
                              hipStream_t stream) {
    const float* h  = (const float*)d_in[0];   // [2,4096,2048]
    const float* Wq = (const float*)d_in[1];   // [256,2048]
    const float* Wk = (const float*)d_in[2];   // [64,2048]
    const float* w  = (const float*)d_in[3];   // [4]
    float* out = (float*)d_out;                // [2,4096,4096]

    char* ws = (char*)d_ws;
    unsigned short* W_swz = (unsigned short*)ws;                       // 1.25 MB
    ws += 2 * (size_t)NCHUNK * BCHUNK;
    char* H_swz = ws;                                                  // 32 MB
    ws += (size_t)256 * STRIP_BYTES;
    unsigned short* QKb = (unsigned short*)ws;                         // 5 MB bf16

    cvt_w_swz<<<320, 256, 0, stream>>>(Wq, Wk, W_swz);
    cvt_h_swz<<<256, 512, 0, stream>>>(h, H_swz);
    proj_gemm<<<dim3(2, 256), 256, 0, stream>>>(H_swz, W_swz, QKb);
    scores_kernel<<<dim3(32, 32, 2), 256, 0, stream>>>(QKb, w, out);
}

// Round 12
// 113.341 us; speedup vs baseline: 1.4201x; 1.0615x over previous
//
#include <hip/hip_runtime.h>

// ---------------- types ----------------
typedef __attribute__((ext_vector_type(8))) short bf16x8;   // 8 bf16 in 4 VGPRs
typedef __attribute__((ext_vector_type(4))) float f32x4;
typedef __attribute__((ext_vector_type(8))) unsigned short us8;

#define K_DIM 2048
#define QK_N  320     // 256 q cols + 64 k cols
#define SEQ   4096
#define BK    64
#define NCHUNK 32                      // K_DIM / BK
#define NHALF  160                     // N columns per block
#define BCHUNK 20480                   // bytes of one B chunk: 8 units * 160 cols * 16B
#define STRIP_BYTES 131072             // 32 rows * 2048 k * 2B = 64 t-steps * 2048B

__device__ __forceinline__ unsigned short f2bf(float f) {
    unsigned int u = __builtin_bit_cast(unsigned int, f);
    u += 0x7FFFu + ((u >> 16) & 1u);      // round-to-nearest-even
    return (unsigned short)(u >> 16);
}

// ---------------- W convert + re-layout ----------------
// ws layout: [2 N-halves][NCHUNK][8 k-units][160 cols][16B]
__global__ void cvt_w_swz(const float* __restrict__ Wq,
                          const float* __restrict__ Wk,
                          unsigned short* __restrict__ ws) {
    int id = blockIdx.x * 256 + threadIdx.x;   // 320*256 ids
    int c  = id >> 8;                          // 0..319 (output col)
    int k8 = id & 255;                         // 8-elem k group
    int k0 = k8 * 8;
    const float* src = (c < 256) ? (Wq + (size_t)c * K_DIM + k0)
                                 : (Wk + (size_t)(c - 256) * K_DIM + k0);
    float4 v0 = *reinterpret_cast<const float4*>(src);
    float4 v1 = *reinterpret_cast<const float4*>(src + 4);
    us8 o;
    o[0] = f2bf(v0.x); o[1] = f2bf(v0.y); o[2] = f2bf(v0.z); o[3] = f2bf(v0.w);
    o[4] = f2bf(v1.x); o[5] = f2bf(v1.y); o[6] = f2bf(v1.z); o[7] = f2bf(v1.w);
    int half = (c >= NHALF) ? 1 : 0;
    int cc   = c - half * NHALF;
    int kc = k0 / BK;            // chunk index 0..31
    int u  = (k0 % BK) >> 3;     // k-unit within chunk (0..7)
    size_t byteoff = (size_t)half * (NCHUNK * (size_t)BCHUNK)
                   + (size_t)kc * BCHUNK + ((size_t)(u * NHALF + cc) * 16);
    *reinterpret_cast<us8*>((char*)ws + byteoff) = o;
}

// ---------------- h convert + re-layout via LDS transpose ----------------
// Output layout: [256 strips][64 t][2 rg][64 lanes][16B]; lane=(lg*16+lr),
// row=rg*16+lr, cols=t*32+lg*8. Reads coalesced, writes contiguous 1KB/wave.
// grid 1024: one block per (strip, k-quarter) -> 4 blocks/CU, 2 barriers only.
__global__ __launch_bounds__(512) void cvt_h_swz(
    const float* __restrict__ h, char* __restrict__ hs) {
    __shared__ char L[32 * 1024];             // [32 rows][512 bf16] swizzled
    const int strip = blockIdx.x >> 2;
    const int q     = blockIdx.x & 3;         // k-quarter: cols [q*512, q*512+512)
    const float* hbase = h + (size_t)strip * 32 * K_DIM;
    char* obase = hs + (size_t)strip * STRIP_BYTES;

    // phase 1: coalesced read + cvt -> swizzled LDS
#pragma unroll
    for (int i = 0; i < 4; ++i) {
        int u = i * 512 + threadIdx.x;    // 0..2047
        int r = u >> 6;                   // row 0..31
        int g = u & 63;                   // 8-col group 0..63
        const float* src = hbase + (size_t)r * K_DIM + q * 512 + g * 8;
        float4 v0 = *reinterpret_cast<const float4*>(src);
        float4 v1 = *reinterpret_cast<const float4*>(src + 4);
        us8 o;
        o[0] = f2bf(v0.x); o[1] = f2bf(v0.y); o[2] = f2bf(v0.z); o[3] = f2bf(v0.w);
        o[4] = f2bf(v1.x); o[5] = f2bf(v1.y); o[6] = f2bf(v1.z); o[7] = f2bf(v1.w);
        int byteoff = r * 1024 + ((g * 16) ^ ((r & 7) << 4));
        *reinterpret_cast<us8*>(L + byteoff) = o;
    }
    __syncthreads();
    // phase 2: LDS -> global in fragment order, contiguous stores
#pragma unroll
    for (int i = 0; i < 4; ++i) {
        int u = i * 512 + threadIdx.x;    // 16B units 0..2047
        int tt  = u >> 7;                 // local t-step 0..15
        int rem = u & 127;
        int rg  = rem >> 6;
        int lane = rem & 63;
        int lg = lane >> 4, lr = lane & 15;
        int row = rg * 16 + lr;
        int lcol16 = tt * 4 + lg;         // 16B slot within row
        int byteoff = row * 1024 + ((lcol16 * 16) ^ ((row & 7) << 4));
        us8 o = *reinterpret_cast<const us8*>(L + byteoff);
        size_t oo = (size_t)(q * 16 + tt) * 2048 + (size_t)rg * 1024
                  + (size_t)lane * 16;
        *reinterpret_cast<us8*>(obase + oo) = o;
    }
}

// ---------------- projection GEMM: QKb[8192][320] = h * W^T (bf16 out) -------
// grid (2 N-halves, 256 M-strips) = 512 blocks x 256 threads (4 waves:
// 2 rg x 2 cg), wave tile 16x80, K=2048. No LDS, no barriers.
// 8-DEEP asm pipeline: 48 global_load_dwordx4 in flight per wave, counted
// s_waitcnt vmcnt(42) steady state (never 0 in loop), drain 42..0 in epilogue.
__global__ __launch_bounds__(256, 2) void proj_gemm(
    const char* __restrict__ Hs,            // h_swz (bf16 frag order)
    const unsigned short* __restrict__ Wsz, // re-laid-out W
    unsigned short* __restrict__ C)         // [8192][320] bf16
{
    const int tid  = threadIdx.x;
    const int lane = tid & 63;
    const int wid  = tid >> 6;          // 0..3
    const int rg   = wid >> 1;          // 0..1 (M row-group)
    const int cg   = wid & 1;           // 0..1 (N col-group)
    const int half = blockIdx.x;
    const int row0 = blockIdx.y * 32 + rg * 16;
    const int lr = lane & 15, lg = lane >> 4;

    const char* ahp = Hs + (size_t)blockIdx.y * STRIP_BYTES
                    + (size_t)rg * 1024 + (size_t)lane * 16;
    const char* wbase = (const char*)Wsz + (size_t)half * (NCHUNK * (size_t)BCHUNK)
                      + ((cg * 80 + lr) << 4);

    f32x4 acc[5];
#pragma unroll
    for (int j = 0; j < 5; ++j) acc[j] = (f32x4)0.f;

#define GLOAD(dst, ptr) \
    asm volatile("global_load_dwordx4 %0, %1, off" : "=v"(dst) : "v"(ptr))

#define WAITV(N) do { \
    asm volatile("s_waitcnt vmcnt(" #N ")" ::: "memory"); \
    __builtin_amdgcn_sched_barrier(0); \
} while (0)

#define ISSUE(u, fa, f0, f1, f2, f3, f4) do { \
    const char* bu_ = wbase + (size_t)((u) >> 1) * BCHUNK \
                    + (size_t)((((u) & 1) * 4 + lg) * NHALF) * 16; \
    GLOAD(f0, bu_); \
    GLOAD(f1, bu_ + 256); \
    GLOAD(f2, bu_ + 512); \
    GLOAD(f3, bu_ + 768); \
    GLOAD(f4, bu_ + 1024); \
    GLOAD(fa, ahp + (size_t)(u) * 2048); \
} while (0)

#define COMPUTE(fa, f0, f1, f2, f3, f4) do { \
    acc[0] = __builtin_amdgcn_mfma_f32_16x16x32_bf16(fa, f0, acc[0], 0, 0, 0); \
    acc[1] = __builtin_amdgcn_mfma_f32_16x16x32_bf16(fa, f1, acc[1], 0, 0, 0); \
    acc[2] = __builtin_amdgcn_mfma_f32_16x16x32_bf16(fa, f2, acc[2], 0, 0, 0); \
    acc[3] = __builtin_amdgcn_mfma_f32_16x16x32_bf16(fa, f3, acc[3], 0, 0, 0); \
    acc[4] = __builtin_amdgcn_mfma_f32_16x16x32_bf16(fa, f4, acc[4], 0, 0, 0); \
} while (0)

    // 8 frag sets (static names — rule #20): 48 bf16x8 = 192 VGPR
    bf16x8 a0, p00, p01, p02, p03, p04;
    bf16x8 a1, p10, p11, p12, p13, p14;
    bf16x8 a2, p20, p21, p22, p23, p24;
    bf16x8 a3, p30, p31, p32, p33, p34;
    bf16x8 a4, p40, p41, p42, p43, p44;
    bf16x8 a5, p50, p51, p52, p53, p54;
    bf16x8 a6, p60, p61, p62, p63, p64;
    bf16x8 a7, p70, p71, p72, p73, p74;

    // prologue: fill the pipeline (48 loads in flight)
    ISSUE(0, a0, p00, p01, p02, p03, p04);
    ISSUE(1, a1, p10, p11, p12, p13, p14);
    ISSUE(2, a2, p20, p21, p22, p23, p24);
    ISSUE(3, a3, p30, p31, p32, p33, p34);
    ISSUE(4, a4, p40, p41, p42, p43, p44);
    ISSUE(5, a5, p50, p51, p52, p53, p54);
    ISSUE(6, a6, p60, p61, p62, p63, p64);
    ISSUE(7, a7, p70, p71, p72, p73, p74);

    for (int t = 0; t < 56; t += 8) {
        WAITV(42); COMPUTE(a0, p00, p01, p02, p03, p04);
        ISSUE(t + 8,  a0, p00, p01, p02, p03, p04);
        WAITV(42); COMPUTE(a1, p10, p11, p12, p13, p14);
        ISSUE(t + 9,  a1, p10, p11, p12, p13, p14);
        WAITV(42); COMPUTE(a2, p20, p21, p22, p23, p24);
        ISSUE(t + 10, a2, p20, p21, p22, p23, p24);
        WAITV(42); COMPUTE(a3, p30, p31, p32, p33, p34);
        ISSUE(t + 11, a3, p30, p31, p32, p33, p34);
        WAITV(42); COMPUTE(a4, p40, p41, p42, p43, p44);
        ISSUE(t + 12, a4, p40, p41, p42, p43, p44);
        WAITV(42); COMPUTE(a5, p50, p51, p52, p53, p54);
        ISSUE(t + 13, a5, p50, p51, p52, p53, p54);
        WAITV(42); COMPUTE(a6, p60, p61, p62, p63, p64);
        ISSUE(t + 14, a6, p60, p61, p62, p63, p64);
        WAITV(42); COMPUTE(a7, p70, p71, p72, p73, p74);
        ISSUE(t + 15, a7, p70, p71, p72, p73, p74);
    }
    // epilogue: drain (t = 56..63)
    WAITV(42); COMPUTE(a0, p00, p01, p02, p03, p04);
    WAITV(36); COMPUTE(a1, p10, p11, p12, p13, p14);
    WAITV(30); COMPUTE(a2, p20, p21, p22, p23, p24);
    WAITV(24); COMPUTE(a3, p30, p31, p32, p33, p34);
    WAITV(18); COMPUTE(a4, p40, p41, p42, p43, p44);
    WAITV(12); COMPUTE(a5, p50, p51, p52, p53, p54);
    WAITV(6);  COMPUTE(a6, p60, p61, p62, p63, p64);
    WAITV(0);  COMPUTE(a7, p70, p71, p72, p73, p74);

#undef GLOAD
#undef WAITV
#undef ISSUE
#undef COMPUTE

    // epilogue: C layout col=lane&15, row=(lane>>4)*4+r
    const int crow = row0 + lg * 4;
    const int ccol = half * NHALF + cg * 80 + lr;
#pragma unroll
    for (int j = 0; j < 5; ++j)
#pragma unroll
        for (int r = 0; r < 4; ++r)
            C[(size_t)(crow + r) * QK_N + ccol + j * 16] = f2bf(acc[j][r]);
}

// ---------------- scores: I[b,t,s] = sum_h w[h]*relu(Q_h K^T) ----------------
// grid (32,32,2); block 256 = 4 waves (2x2). block tile 128x128, wave tile 64x64.
__global__ __launch_bounds__(256) void scores_kernel(
    const unsigned short* __restrict__ QK,   // [B][4096][320] bf16
    const float* __restrict__ w,             // [4]
    float* __restrict__ out)                 // [B][4096][4096] fp32
{
    const int lane = threadIdx.x & 63;
    const int wid  = threadIdx.x >> 6;
    const int b  = blockIdx.z;
    const int t0 = blockIdx.y * 128 + (wid >> 1) * 64;
    const int s0 = blockIdx.x * 128 + (wid & 1) * 64;

    const int lr = lane & 15;
    const int lk = (lane >> 4) * 8;
    const int lg = lane >> 4;

    const unsigned short* Qb = QK + (size_t)b * SEQ * QK_N;
    const unsigned short* Kb = Qb + 256;

    float wv[4] = { w[0], w[1], w[2], w[3] };

    f32x4 fin[4][4];
#pragma unroll
    for (int i = 0; i < 4; ++i)
#pragma unroll
        for (int j = 0; j < 4; ++j) fin[i][j] = (f32x4)0.f;

    const unsigned short* qp = Qb + (size_t)(t0 + lr) * QK_N + lk;
    const unsigned short* kp = Kb + (size_t)(s0 + lr) * QK_N + lk;

#pragma unroll
    for (int h = 0; h < 4; ++h) {
        f32x4 acc[4][4];
#pragma unroll
        for (int i = 0; i < 4; ++i)
#pragma unroll
            for (int j = 0; j < 4; ++j) acc[i][j] = (f32x4)0.f;

#pragma unroll
        for (int ks = 0; ks < 2; ++ks) {
            bf16x8 qf[4], kf[4];
#pragma unroll
            for (int i = 0; i < 4; ++i)
                qf[i] = *reinterpret_cast<const bf16x8*>(
                    qp + (size_t)i * 16 * QK_N + h * 64 + ks * 32);
#pragma unroll
            for (int j = 0; j < 4; ++j)
                kf[j] = *reinterpret_cast<const bf16x8*>(
                    kp + (size_t)j * 16 * QK_N + ks * 32);
            // swapped: a=K (s in reg dim), b=Q (t on lane&15)
#pragma unroll
            for (int i = 0; i < 4; ++i)
#pragma unroll
                for (int j = 0; j < 4; ++j)
                    acc[i][j] = __builtin_amdgcn_mfma_f32_16x16x32_bf16(kf[j], qf[i], acc[i][j], 0, 0, 0);
        }
#pragma unroll
        for (int i = 0; i < 4; ++i)
#pragma unroll
            for (int j = 0; j < 4; ++j)
#pragma unroll
                for (int r = 0; r < 4; ++r)
                    fin[i][j][r] += wv[h] * fmaxf(acc[i][j][r], 0.f);
    }

    // store: lane holds t = t0+i*16+lr, s = s0+j*16+lg*4 .. +3 (contiguous)
    float* ob = out + (size_t)b * SEQ * SEQ;
#pragma unroll
    for (int i = 0; i < 4; ++i) {
        const size_t rbase = (size_t)(t0 + i * 16 + lr) * SEQ + s0 + lg * 4;
#pragma unroll
        for (int j = 0; j < 4; ++j) {
            float4 v;
            v.x = fin[i][j][0]; v.y = fin[i][j][1];
            v.z = fin[i][j][2]; v.w = fin[i][j][3];
            *reinterpret_cast<float4*>(&ob[rbase + j * 16]) = v;
        }
    }
}

// ---------------- launch ----------------
extern "C" void kernel_launch(void* const* d_in, const int* in_sizes, int n_in,
                              void* d_out, int out_size, void* d_ws, size_t ws_size,
                              hipStream_t stream) {
    const float* h  = (const float*)d_in[0];   // [2,4096,2048]
    const float* Wq = (const float*)d_in[1];   // [256,2048]
    const float* Wk = (const float*)d_in[2];   // [64,2048]
    const float* w  = (const float*)d_in[3];   // [4]
    float* out = (float*)d_out;                // [2,4096,4096]

    char* ws = (char*)d_ws;
    unsigned short* W_swz = (unsigned short*)ws;                       // 1.25 MB
    ws += 2 * (size_t)NCHUNK * BCHUNK;
    char* H_swz = ws;                                                  // 32 MB
    ws += (size_t)256 * STRIP_BYTES;
    unsigned short* QKb = (unsigned short*)ws;                         // 5 MB bf16

    cvt_w_swz<<<320, 256, 0, stream>>>(Wq, Wk, W_swz);
    cvt_h_swz<<<1024, 512, 0, stream>>>(h, H_swz);
    proj_gemm<<<dim3(2, 256), 256, 0, stream>>>(H_swz, W_swz, QKb);
    scores_kernel<<<dim3(32, 32, 2), 256, 0, stream>>>(QKb, w, out);
}